// Round 17
// baseline (248.133 us; speedup 1.0000x reference)
//
#include <hip/hip_runtime.h>
#include <math.h>

#define H 18
#define NS 65536
#define AD 4
#define HAD 72
#define ITERS 6
#define DELTA 16.0f
#define SCAP 2048
#define NCH 2048          // 32-candidate chunks per candidate set

__device__ __forceinline__ unsigned encf(float f) {
    unsigned u = __float_as_uint(f);
    return (u & 0x80000000u) ? ~u : (u | 0x80000000u);
}
__device__ __forceinline__ float decf(unsigned u) {
    return __uint_as_float((u & 0x80000000u) ? (u & 0x7FFFFFFFu) : ~u);
}
__device__ __forceinline__ float clamp4f(float x) { return fminf(fmaxf(x, -4.0f), 4.0f); }
// descending u64 order == value desc, then index asc (matches top_k tie-break)
__device__ __forceinline__ unsigned long long packkey(float v, unsigned idx) {
    return ((unsigned long long)encf(v) << 32) | (unsigned long long)(~idx);
}

#define QH0(q) ((q) == 0 ? 0 : (q) == 1 ? 5 : (q) == 2 ? 10 : 14)
#define QCN(q) ((q) < 2 ? 5 : 4)

// ---- iter 0: evaluate pi and cem0. 4 lanes per candidate (h-quarters),
//      10 hoisted float4 loads per lane; 1024 blocks.
__global__ void __launch_bounds__(256, 4) k_value0(
        const float4* __restrict__ pi4, const float4* __restrict__ nz4,
        const float* __restrict__ target, float* __restrict__ meanarr,
        float* __restrict__ v_pi, float* __restrict__ wmax_pi,
        float* __restrict__ v_c0, float* __restrict__ wmax_c0) {
    __shared__ float tgt[HAD], mnL[HAD];
    __shared__ float smaxc[4], smaxp[4];
    const int tid = threadIdx.x, wg = blockIdx.x;
    const int lane = tid & 63, wid = tid >> 6;
    const int q = lane >> 4, s = lane & 15;
    const int n = wg * 64 + wid * 16 + s;
    const int h0 = QH0(q), cnt = QCN(q);

    float4 xs0 = nz4[(size_t)(h0 + 0) * NS + n];
    float4 xs1 = nz4[(size_t)(h0 + 1) * NS + n];
    float4 xs2 = nz4[(size_t)(h0 + 2) * NS + n];
    float4 xs3 = nz4[(size_t)(h0 + 3) * NS + n];
    const int h4 = (h0 + 4 > 17) ? 17 : h0 + 4;
    float4 xs4 = nz4[(size_t)h4 * NS + n];
    float4 ps0 = pi4[(size_t)(h0 + 0) * NS + n];
    float4 ps1 = pi4[(size_t)(h0 + 1) * NS + n];
    float4 ps2 = pi4[(size_t)(h0 + 2) * NS + n];
    float4 ps3 = pi4[(size_t)(h0 + 3) * NS + n];
    float4 ps4 = pi4[(size_t)h4 * NS + n];

    if (tid < HAD) {
        tgt[tid] = target[tid];
        float m0 = ((const float*)pi4)[(size_t)(tid >> 2) * NS * AD + (tid & 3)];
        mnL[tid] = m0;
        meanarr[tid] = m0;   // identical from all blocks: benign
    }
    __syncthreads();

    const float w4 = (cnt == 5) ? 1.0f : 0.0f;
    float a2 = 0.f, p2 = 0.f;
    {
        float c; int h;
        h = h0 + 0;
        c = clamp4f(mnL[h*4+0] + 0.5f*xs0.x) - tgt[h*4+0]; a2 += c*c;
        c = clamp4f(mnL[h*4+1] + 0.5f*xs0.y) - tgt[h*4+1]; a2 += c*c;
        c = clamp4f(mnL[h*4+2] + 0.5f*xs0.z) - tgt[h*4+2]; a2 += c*c;
        c = clamp4f(mnL[h*4+3] + 0.5f*xs0.w) - tgt[h*4+3]; a2 += c*c;
        c = ps0.x - tgt[h*4+0]; p2 += c*c;  c = ps0.y - tgt[h*4+1]; p2 += c*c;
        c = ps0.z - tgt[h*4+2]; p2 += c*c;  c = ps0.w - tgt[h*4+3]; p2 += c*c;
        h = h0 + 1;
        c = clamp4f(mnL[h*4+0] + 0.5f*xs1.x) - tgt[h*4+0]; a2 += c*c;
        c = clamp4f(mnL[h*4+1] + 0.5f*xs1.y) - tgt[h*4+1]; a2 += c*c;
        c = clamp4f(mnL[h*4+2] + 0.5f*xs1.z) - tgt[h*4+2]; a2 += c*c;
        c = clamp4f(mnL[h*4+3] + 0.5f*xs1.w) - tgt[h*4+3]; a2 += c*c;
        c = ps1.x - tgt[h*4+0]; p2 += c*c;  c = ps1.y - tgt[h*4+1]; p2 += c*c;
        c = ps1.z - tgt[h*4+2]; p2 += c*c;  c = ps1.w - tgt[h*4+3]; p2 += c*c;
        h = h0 + 2;
        c = clamp4f(mnL[h*4+0] + 0.5f*xs2.x) - tgt[h*4+0]; a2 += c*c;
        c = clamp4f(mnL[h*4+1] + 0.5f*xs2.y) - tgt[h*4+1]; a2 += c*c;
        c = clamp4f(mnL[h*4+2] + 0.5f*xs2.z) - tgt[h*4+2]; a2 += c*c;
        c = clamp4f(mnL[h*4+3] + 0.5f*xs2.w) - tgt[h*4+3]; a2 += c*c;
        c = ps2.x - tgt[h*4+0]; p2 += c*c;  c = ps2.y - tgt[h*4+1]; p2 += c*c;
        c = ps2.z - tgt[h*4+2]; p2 += c*c;  c = ps2.w - tgt[h*4+3]; p2 += c*c;
        h = h0 + 3;
        c = clamp4f(mnL[h*4+0] + 0.5f*xs3.x) - tgt[h*4+0]; a2 += c*c;
        c = clamp4f(mnL[h*4+1] + 0.5f*xs3.y) - tgt[h*4+1]; a2 += c*c;
        c = clamp4f(mnL[h*4+2] + 0.5f*xs3.z) - tgt[h*4+2]; a2 += c*c;
        c = clamp4f(mnL[h*4+3] + 0.5f*xs3.w) - tgt[h*4+3]; a2 += c*c;
        c = ps3.x - tgt[h*4+0]; p2 += c*c;  c = ps3.y - tgt[h*4+1]; p2 += c*c;
        c = ps3.z - tgt[h*4+2]; p2 += c*c;  c = ps3.w - tgt[h*4+3]; p2 += c*c;
        h = h4;
        c = clamp4f(mnL[h*4+0] + 0.5f*xs4.x) - tgt[h*4+0]; a2 += w4*c*c;
        c = clamp4f(mnL[h*4+1] + 0.5f*xs4.y) - tgt[h*4+1]; a2 += w4*c*c;
        c = clamp4f(mnL[h*4+2] + 0.5f*xs4.z) - tgt[h*4+2]; a2 += w4*c*c;
        c = clamp4f(mnL[h*4+3] + 0.5f*xs4.w) - tgt[h*4+3]; a2 += w4*c*c;
        c = ps4.x - tgt[h*4+0]; p2 += w4*c*c;  c = ps4.y - tgt[h*4+1]; p2 += w4*c*c;
        c = ps4.z - tgt[h*4+2]; p2 += w4*c*c;  c = ps4.w - tgt[h*4+3]; p2 += w4*c*c;
    }
    a2 += __shfl_xor(a2, 16);  a2 += __shfl_xor(a2, 32);
    p2 += __shfl_xor(p2, 16);  p2 += __shfl_xor(p2, 32);
    const float vc = -a2, vp = -p2;
    if (lane < 16) { v_c0[n] = vc; v_pi[n] = vp; }
    float mc = vc, mp = vp;
#pragma unroll
    for (int off = 8; off; off >>= 1) {
        mc = fmaxf(mc, __shfl_xor(mc, off));
        mp = fmaxf(mp, __shfl_xor(mp, off));
    }
    if (lane == 0) { smaxc[wid] = mc; smaxp[wid] = mp; }
    __syncthreads();
    if (tid == 0) {
        wmax_c0[wg * 2 + 0] = fmaxf(smaxc[0], smaxc[1]);
        wmax_c0[wg * 2 + 1] = fmaxf(smaxc[2], smaxc[3]);
        wmax_pi[wg * 2 + 0] = fmaxf(smaxp[0], smaxp[1]);
        wmax_pi[wg * 2 + 1] = fmaxf(smaxp[2], smaxp[3]);
    }
}

// ---- iters 1..5 fused: EVERY block redundantly reduces iter-1 with the
//      cheap chain (maxima scan -> survivors -> rank-select top-64 ->
//      softmax -> float4 gather -> mean), then evaluates its 64 candidates.
__global__ void __launch_bounds__(256, 2) k_fused(
        const float* __restrict__ pi, const float* __restrict__ noise,
        const float* __restrict__ target, float* __restrict__ meanarr,
        const float* __restrict__ wmax_pi, const float* __restrict__ v_pi,
        const float* __restrict__ wmax_prev, const float* __restrict__ v_prev,
        float* __restrict__ v_out, float* __restrict__ wmax_out, int iter) {
    __shared__ unsigned long long skey[SCAP];
    __shared__ unsigned long long top[64];
    __shared__ float buf[64 * 76];
    __shared__ float w64[64];
    __shared__ float tgt[HAD], mnL[HAD], mprev[HAD];
    __shared__ float redf[4];
    __shared__ unsigned s_fcnt;
    __shared__ float s_S, s_gmax;
    __shared__ float smax[4];

    const int tid = threadIdx.x, wg = blockIdx.x;
    const int lane = tid & 63, wid = tid >> 6;

    if (tid < HAD) {
        tgt[tid] = target[tid];
        mprev[tid] = meanarr[(size_t)(iter - 1) * HAD + tid];
    }
    if (tid == 0) s_fcnt = 0u;
    __syncthreads();

    // ---- gmax over pi ∪ cem_{iter-1} chunk maxima
    {
        float g = -INFINITY;
#pragma unroll
        for (int r = 0; r < 8; ++r) {
            const int k = tid + r * 256;
            g = fmaxf(g, fmaxf(wmax_pi[k], wmax_prev[k]));
        }
        for (int off = 32; off; off >>= 1) g = fmaxf(g, __shfl_xor(g, off));
        if (lane == 0) redf[wid] = g;
        __syncthreads();
        if (tid == 0)
            s_gmax = fmaxf(fmaxf(redf[0], redf[1]), fmaxf(redf[2], redf[3]));
        __syncthreads();
    }
    const float gmax = s_gmax, thr = gmax - DELTA;

    // ---- survivors from passing chunks only
#pragma unroll
    for (int r = 0; r < 8; ++r) {
        const int c = tid + r * 256;
        if (wmax_pi[c] >= thr) {
            const float4* v4 = (const float4*)v_pi + c * 8;
            for (int q = 0; q < 8; ++q) {
                float4 x = v4[q];
                float vv[4] = {x.x, x.y, x.z, x.w};
#pragma unroll
                for (int c2 = 0; c2 < 4; ++c2)
                    if (vv[c2] >= thr) {
                        unsigned p = atomicAdd(&s_fcnt, 1u);
                        if (p < SCAP) skey[p] = packkey(vv[c2], (unsigned)(c * 32 + q * 4 + c2));
                    }
            }
        }
        if (wmax_prev[c] >= thr) {
            const float4* v4 = (const float4*)v_prev + c * 8;
            for (int q = 0; q < 8; ++q) {
                float4 x = v4[q];
                float vv[4] = {x.x, x.y, x.z, x.w};
#pragma unroll
                for (int c2 = 0; c2 < 4; ++c2)
                    if (vv[c2] >= thr) {
                        unsigned p = atomicAdd(&s_fcnt, 1u);
                        if (p < SCAP) skey[p] = packkey(vv[c2], (unsigned)(NS + c * 32 + q * 4 + c2));
                    }
            }
        }
    }
    __syncthreads();
    unsigned fc = s_fcnt; if (fc > SCAP) fc = SCAP;

    // ---- rank-select exact sorted top-64 (2 barriers)
    for (unsigned i = tid; i < fc; i += 256) {
        unsigned long long k = skey[i];
        unsigned r = 0;
        for (unsigned j = 0; j < fc; ++j) r += (skey[j] > k) ? 1u : 0u;
        if (r < 64u) top[r] = k;
    }
    if (fc < 64u)
        for (unsigned r = fc + tid; r < 64u; r += 256) top[r] = 0ull;
    __syncthreads();
    const int E = (fc < 64u) ? (int)fc : 64;

    if (tid < 64) {
        float we = (tid < E) ? expf(decf((unsigned)(top[tid] >> 32)) - gmax) : 0.0f;
        w64[tid] = we;
        float s = we;
        for (int off = 32; off; off >>= 1) s += __shfl_xor(s, off);
        if (tid == 0) s_S = s;
    }
    __syncthreads();
    const float invS = 1.0f / (s_S * (1.0f + 1e-9f));

    // ---- elite gather (float4 per (e,h)), weighted into buf
    const float pscale = (iter == 1) ? 0.5f : 1.0f;
    const float4* pi4 = (const float4*)pi;
    const float4* nzp4 = (const float4*)(noise + (size_t)(iter - 1) * H * NS * AD);
    for (int el = tid; el < 64 * H; el += 256) {
        const int e = el / H, h = el - e * H;
        float ax = 0.f, ay = 0.f, az = 0.f, aw = 0.f;
        if (e < E) {
            const unsigned idx = (unsigned)~(unsigned)(top[e] & 0xFFFFFFFFull);
            float4 a;
            if (idx < NS) {
                a = pi4[(size_t)h * NS + idx];
            } else {
                float4 nz = nzp4[(size_t)h * NS + (idx - NS)];
                a.x = clamp4f(mprev[h*4+0] + pscale * nz.x);
                a.y = clamp4f(mprev[h*4+1] + pscale * nz.y);
                a.z = clamp4f(mprev[h*4+2] + pscale * nz.z);
                a.w = clamp4f(mprev[h*4+3] + pscale * nz.w);
            }
            const float we = w64[e];
            ax = we * a.x; ay = we * a.y; az = we * a.z; aw = we * a.w;
        }
        buf[e * 76 + h * 4 + 0] = ax;
        buf[e * 76 + h * 4 + 1] = ay;
        buf[e * 76 + h * 4 + 2] = az;
        buf[e * 76 + h * 4 + 3] = aw;
    }
    __syncthreads();
    if (tid < HAD) {
        float s = 0.f;
#pragma unroll 8
        for (int e = 0; e < 64; ++e) s += buf[e * 76 + tid];
        float nm = 0.1f * mprev[tid] + 0.9f * (s * invS);
        mnL[tid] = nm;
        meanarr[(size_t)iter * HAD + tid] = nm;   // identical dup write: benign
    }
    __syncthreads();

    // ---- phase A: evaluate cem_iter (scale = 1.0), 4 lanes per candidate
    const int q = lane >> 4, s2 = lane & 15;
    const int n = wg * 64 + wid * 16 + s2;
    const int h0 = QH0(q), cnt = QCN(q);
    const float4* nz4 = (const float4*)(noise + (size_t)iter * H * NS * AD);
    float4 xs0 = nz4[(size_t)(h0 + 0) * NS + n];
    float4 xs1 = nz4[(size_t)(h0 + 1) * NS + n];
    float4 xs2 = nz4[(size_t)(h0 + 2) * NS + n];
    float4 xs3 = nz4[(size_t)(h0 + 3) * NS + n];
    const int h4 = (h0 + 4 > 17) ? 17 : h0 + 4;
    float4 xs4 = nz4[(size_t)h4 * NS + n];

    const float w4 = (cnt == 5) ? 1.0f : 0.0f;
    float a2 = 0.f;
    {
        float c; int h;
        h = h0 + 0;
        c = clamp4f(mnL[h*4+0] + xs0.x) - tgt[h*4+0]; a2 += c*c;
        c = clamp4f(mnL[h*4+1] + xs0.y) - tgt[h*4+1]; a2 += c*c;
        c = clamp4f(mnL[h*4+2] + xs0.z) - tgt[h*4+2]; a2 += c*c;
        c = clamp4f(mnL[h*4+3] + xs0.w) - tgt[h*4+3]; a2 += c*c;
        h = h0 + 1;
        c = clamp4f(mnL[h*4+0] + xs1.x) - tgt[h*4+0]; a2 += c*c;
        c = clamp4f(mnL[h*4+1] + xs1.y) - tgt[h*4+1]; a2 += c*c;
        c = clamp4f(mnL[h*4+2] + xs1.z) - tgt[h*4+2]; a2 += c*c;
        c = clamp4f(mnL[h*4+3] + xs1.w) - tgt[h*4+3]; a2 += c*c;
        h = h0 + 2;
        c = clamp4f(mnL[h*4+0] + xs2.x) - tgt[h*4+0]; a2 += c*c;
        c = clamp4f(mnL[h*4+1] + xs2.y) - tgt[h*4+1]; a2 += c*c;
        c = clamp4f(mnL[h*4+2] + xs2.z) - tgt[h*4+2]; a2 += c*c;
        c = clamp4f(mnL[h*4+3] + xs2.w) - tgt[h*4+3]; a2 += c*c;
        h = h0 + 3;
        c = clamp4f(mnL[h*4+0] + xs3.x) - tgt[h*4+0]; a2 += c*c;
        c = clamp4f(mnL[h*4+1] + xs3.y) - tgt[h*4+1]; a2 += c*c;
        c = clamp4f(mnL[h*4+2] + xs3.z) - tgt[h*4+2]; a2 += c*c;
        c = clamp4f(mnL[h*4+3] + xs3.w) - tgt[h*4+3]; a2 += c*c;
        h = h4;
        c = clamp4f(mnL[h*4+0] + xs4.x) - tgt[h*4+0]; a2 += w4*c*c;
        c = clamp4f(mnL[h*4+1] + xs4.y) - tgt[h*4+1]; a2 += w4*c*c;
        c = clamp4f(mnL[h*4+2] + xs4.z) - tgt[h*4+2]; a2 += w4*c*c;
        c = clamp4f(mnL[h*4+3] + xs4.w) - tgt[h*4+3]; a2 += w4*c*c;
    }
    a2 += __shfl_xor(a2, 16);  a2 += __shfl_xor(a2, 32);
    const float vc = -a2;
    if (lane < 16) v_out[n] = vc;
    float m = vc;
#pragma unroll
    for (int off = 8; off; off >>= 1) m = fmaxf(m, __shfl_xor(m, off));
    if (lane == 0) smax[wid] = m;
    __syncthreads();
    if (tid == 0) {
        wmax_out[wg * 2 + 0] = fmaxf(smax[0], smax[1]);
        wmax_out[wg * 2 + 1] = fmaxf(smax[2], smax[3]);
    }
}

// ---- final: exact argmax over pi ∪ cem5 survivors, gather, write out
__global__ void __launch_bounds__(1024) k_final(
        const float* __restrict__ pi, const float* __restrict__ noise_i,
        const float* __restrict__ meanarr,
        const float* __restrict__ wmax_pi, const float* __restrict__ v_pi,
        const float* __restrict__ wmax_c, const float* __restrict__ v_c,
        float* __restrict__ out) {
    __shared__ unsigned long long redk[16];
    __shared__ float mprev[HAD];
    __shared__ float redf[16];
    __shared__ float s_gmax;
    const int tid = threadIdx.x, lane = tid & 63, wid = tid >> 6;

    if (tid < HAD) mprev[tid] = meanarr[(size_t)5 * HAD + tid];
    {
        float g = fmaxf(fmaxf(wmax_pi[tid], wmax_pi[tid + 1024]),
                        fmaxf(wmax_c[tid], wmax_c[tid + 1024]));
        for (int off = 32; off; off >>= 1) g = fmaxf(g, __shfl_xor(g, off));
        if (lane == 0) redf[wid] = g;
        __syncthreads();
        if (tid == 0) {
            float x = redf[0];
            for (int q = 1; q < 16; ++q) x = fmaxf(x, redf[q]);
            s_gmax = x;
        }
        __syncthreads();
    }
    const float gmax = s_gmax;
    unsigned long long bk = 0ull;
#pragma unroll
    for (int r = 0; r < 2; ++r) {
        const int c = tid + r * 1024;
        if (wmax_pi[c] >= gmax) {
            const float4* v4 = (const float4*)v_pi + c * 8;
            for (int q = 0; q < 8; ++q) {
                float4 x = v4[q];
                float vv[4] = {x.x, x.y, x.z, x.w};
#pragma unroll
                for (int c2 = 0; c2 < 4; ++c2)
                    if (vv[c2] >= gmax) {
                        unsigned long long key = packkey(vv[c2], (unsigned)(c * 32 + q * 4 + c2));
                        if (key > bk) bk = key;
                    }
            }
        }
        if (wmax_c[c] >= gmax) {
            const float4* v4 = (const float4*)v_c + c * 8;
            for (int q = 0; q < 8; ++q) {
                float4 x = v4[q];
                float vv[4] = {x.x, x.y, x.z, x.w};
#pragma unroll
                for (int c2 = 0; c2 < 4; ++c2)
                    if (vv[c2] >= gmax) {
                        unsigned long long key = packkey(vv[c2], (unsigned)(NS + c * 32 + q * 4 + c2));
                        if (key > bk) bk = key;
                    }
            }
        }
    }
    for (int off = 32; off; off >>= 1) {
        unsigned long long ok = __shfl_xor(bk, off);
        if (ok > bk) bk = ok;
    }
    if (lane == 0) redk[wid] = bk;
    __syncthreads();
    if (tid == 0) {
        unsigned long long b = redk[0];
        for (int q = 1; q < 16; ++q) if (redk[q] > b) b = redk[q];
        redk[0] = b;
    }
    __syncthreads();
    const unsigned idx = (unsigned)~(unsigned)(redk[0] & 0xFFFFFFFFull);
    if (tid < HAD) {
        const int h = tid >> 2, aa = tid & 3;
        float o;
        if (idx < NS) o = pi[(size_t)h * NS * AD + (size_t)idx * AD + aa];
        else o = clamp4f(mprev[tid] + noise_i[(size_t)h * NS * AD + (size_t)(idx - NS) * AD + aa]);
        out[tid] = o;
    }
}

extern "C" void kernel_launch(void* const* d_in, const int* in_sizes, int n_in,
                              void* d_out, int out_size, void* d_ws, size_t ws_size,
                              hipStream_t stream) {
    const float* pi     = (const float*)d_in[0];
    const float* noise  = (const float*)d_in[1];
    const float* target = (const float*)d_in[2];
    float* out = (float*)d_out;

    float* ws = (float*)d_ws;
    float* meanarr = ws;                                   // 8*72 (pad 1024)
    float* wmax_pi = ws + 1024;                            // NCH
    float* wmax_c  = wmax_pi + NCH;                        // 6*NCH
    float* v_pi    = wmax_c + 6 * NCH;                     // NS
    float* v_c     = v_pi + NS;                            // 6*NS

    k_value0<<<1024, 256, 0, stream>>>((const float4*)pi, (const float4*)noise,
                                       target, meanarr, v_pi, wmax_pi, v_c, wmax_c);
    for (int i = 1; i < ITERS; ++i)
        k_fused<<<1024, 256, 0, stream>>>(pi, noise, target, meanarr,
                                          wmax_pi, v_pi,
                                          wmax_c + (size_t)(i - 1) * NCH,
                                          v_c + (size_t)(i - 1) * NS,
                                          v_c + (size_t)i * NS,
                                          wmax_c + (size_t)i * NCH, i);
    k_final<<<1, 1024, 0, stream>>>(pi, noise + (size_t)5 * H * NS * AD, meanarr,
                                    wmax_pi, v_pi,
                                    wmax_c + (size_t)5 * NCH,
                                    v_c + (size_t)5 * NS, out);
}

// Round 18
// 157.736 us; speedup vs baseline: 1.5731x; 1.5731x over previous
//
#include <hip/hip_runtime.h>
#include <math.h>

#define H 18
#define NS 65536
#define AD 4
#define HAD 72
#define ITERS 6
#define DELTA 16.0f
#define SCAP 4096
#define NCH 2048          // 32-candidate chunks per candidate set

__device__ __forceinline__ unsigned encf(float f) {
    unsigned u = __float_as_uint(f);
    return (u & 0x80000000u) ? ~u : (u | 0x80000000u);
}
__device__ __forceinline__ float decf(unsigned u) {
    return __uint_as_float((u & 0x80000000u) ? (u & 0x7FFFFFFFu) : ~u);
}
__device__ __forceinline__ float clamp4f(float x) { return fminf(fmaxf(x, -4.0f), 4.0f); }
// descending u64 order == value desc, then index asc (matches top_k tie-break)
__device__ __forceinline__ unsigned long long packkey(float v, unsigned idx) {
    return ((unsigned long long)encf(v) << 32) | (unsigned long long)(~idx);
}

#define QH0(q) ((q) == 0 ? 0 : (q) == 1 ? 5 : (q) == 2 ? 10 : 14)
#define QCN(q) ((q) < 2 ? 5 : 4)

// ---- iter 0: evaluate pi and cem0. 4 lanes per candidate (h-quarters),
//      10 hoisted float4 loads per lane; 1024 blocks.
__global__ void __launch_bounds__(256, 4) k_value0(
        const float4* __restrict__ pi4, const float4* __restrict__ nz4,
        const float* __restrict__ target, float* __restrict__ meanarr,
        float* __restrict__ v_pi, float* __restrict__ wmax_pi,
        float* __restrict__ v_c0, float* __restrict__ wmax_c0) {
    __shared__ float tgt[HAD], mnL[HAD];
    __shared__ float smaxc[4], smaxp[4];
    const int tid = threadIdx.x, wg = blockIdx.x;
    const int lane = tid & 63, wid = tid >> 6;
    const int q = lane >> 4, s = lane & 15;
    const int n = wg * 64 + wid * 16 + s;
    const int h0 = QH0(q), cnt = QCN(q);

    float4 xs0 = nz4[(size_t)(h0 + 0) * NS + n];
    float4 xs1 = nz4[(size_t)(h0 + 1) * NS + n];
    float4 xs2 = nz4[(size_t)(h0 + 2) * NS + n];
    float4 xs3 = nz4[(size_t)(h0 + 3) * NS + n];
    const int h4 = (h0 + 4 > 17) ? 17 : h0 + 4;
    float4 xs4 = nz4[(size_t)h4 * NS + n];
    float4 ps0 = pi4[(size_t)(h0 + 0) * NS + n];
    float4 ps1 = pi4[(size_t)(h0 + 1) * NS + n];
    float4 ps2 = pi4[(size_t)(h0 + 2) * NS + n];
    float4 ps3 = pi4[(size_t)(h0 + 3) * NS + n];
    float4 ps4 = pi4[(size_t)h4 * NS + n];

    if (tid < HAD) {
        tgt[tid] = target[tid];
        float m0 = ((const float*)pi4)[(size_t)(tid >> 2) * NS * AD + (tid & 3)];
        mnL[tid] = m0;
        meanarr[tid] = m0;   // identical from all blocks: benign
    }
    __syncthreads();

    const float w4 = (cnt == 5) ? 1.0f : 0.0f;
    float a2 = 0.f, p2 = 0.f;
    {
        float c; int h;
        h = h0 + 0;
        c = clamp4f(mnL[h*4+0] + 0.5f*xs0.x) - tgt[h*4+0]; a2 += c*c;
        c = clamp4f(mnL[h*4+1] + 0.5f*xs0.y) - tgt[h*4+1]; a2 += c*c;
        c = clamp4f(mnL[h*4+2] + 0.5f*xs0.z) - tgt[h*4+2]; a2 += c*c;
        c = clamp4f(mnL[h*4+3] + 0.5f*xs0.w) - tgt[h*4+3]; a2 += c*c;
        c = ps0.x - tgt[h*4+0]; p2 += c*c;  c = ps0.y - tgt[h*4+1]; p2 += c*c;
        c = ps0.z - tgt[h*4+2]; p2 += c*c;  c = ps0.w - tgt[h*4+3]; p2 += c*c;
        h = h0 + 1;
        c = clamp4f(mnL[h*4+0] + 0.5f*xs1.x) - tgt[h*4+0]; a2 += c*c;
        c = clamp4f(mnL[h*4+1] + 0.5f*xs1.y) - tgt[h*4+1]; a2 += c*c;
        c = clamp4f(mnL[h*4+2] + 0.5f*xs1.z) - tgt[h*4+2]; a2 += c*c;
        c = clamp4f(mnL[h*4+3] + 0.5f*xs1.w) - tgt[h*4+3]; a2 += c*c;
        c = ps1.x - tgt[h*4+0]; p2 += c*c;  c = ps1.y - tgt[h*4+1]; p2 += c*c;
        c = ps1.z - tgt[h*4+2]; p2 += c*c;  c = ps1.w - tgt[h*4+3]; p2 += c*c;
        h = h0 + 2;
        c = clamp4f(mnL[h*4+0] + 0.5f*xs2.x) - tgt[h*4+0]; a2 += c*c;
        c = clamp4f(mnL[h*4+1] + 0.5f*xs2.y) - tgt[h*4+1]; a2 += c*c;
        c = clamp4f(mnL[h*4+2] + 0.5f*xs2.z) - tgt[h*4+2]; a2 += c*c;
        c = clamp4f(mnL[h*4+3] + 0.5f*xs2.w) - tgt[h*4+3]; a2 += c*c;
        c = ps2.x - tgt[h*4+0]; p2 += c*c;  c = ps2.y - tgt[h*4+1]; p2 += c*c;
        c = ps2.z - tgt[h*4+2]; p2 += c*c;  c = ps2.w - tgt[h*4+3]; p2 += c*c;
        h = h0 + 3;
        c = clamp4f(mnL[h*4+0] + 0.5f*xs3.x) - tgt[h*4+0]; a2 += c*c;
        c = clamp4f(mnL[h*4+1] + 0.5f*xs3.y) - tgt[h*4+1]; a2 += c*c;
        c = clamp4f(mnL[h*4+2] + 0.5f*xs3.z) - tgt[h*4+2]; a2 += c*c;
        c = clamp4f(mnL[h*4+3] + 0.5f*xs3.w) - tgt[h*4+3]; a2 += c*c;
        c = ps3.x - tgt[h*4+0]; p2 += c*c;  c = ps3.y - tgt[h*4+1]; p2 += c*c;
        c = ps3.z - tgt[h*4+2]; p2 += c*c;  c = ps3.w - tgt[h*4+3]; p2 += c*c;
        h = h4;
        c = clamp4f(mnL[h*4+0] + 0.5f*xs4.x) - tgt[h*4+0]; a2 += w4*c*c;
        c = clamp4f(mnL[h*4+1] + 0.5f*xs4.y) - tgt[h*4+1]; a2 += w4*c*c;
        c = clamp4f(mnL[h*4+2] + 0.5f*xs4.z) - tgt[h*4+2]; a2 += w4*c*c;
        c = clamp4f(mnL[h*4+3] + 0.5f*xs4.w) - tgt[h*4+3]; a2 += w4*c*c;
        c = ps4.x - tgt[h*4+0]; p2 += w4*c*c;  c = ps4.y - tgt[h*4+1]; p2 += w4*c*c;
        c = ps4.z - tgt[h*4+2]; p2 += w4*c*c;  c = ps4.w - tgt[h*4+3]; p2 += w4*c*c;
    }
    a2 += __shfl_xor(a2, 16);  a2 += __shfl_xor(a2, 32);
    p2 += __shfl_xor(p2, 16);  p2 += __shfl_xor(p2, 32);
    const float vc = -a2, vp = -p2;
    if (lane < 16) { v_c0[n] = vc; v_pi[n] = vp; }
    float mc = vc, mp = vp;
#pragma unroll
    for (int off = 8; off; off >>= 1) {
        mc = fmaxf(mc, __shfl_xor(mc, off));
        mp = fmaxf(mp, __shfl_xor(mp, off));
    }
    if (lane == 0) { smaxc[wid] = mc; smaxp[wid] = mp; }
    __syncthreads();
    if (tid == 0) {
        wmax_c0[wg * 2 + 0] = fmaxf(smaxc[0], smaxc[1]);
        wmax_c0[wg * 2 + 1] = fmaxf(smaxc[2], smaxc[3]);
        wmax_pi[wg * 2 + 0] = fmaxf(smaxp[0], smaxp[1]);
        wmax_pi[wg * 2 + 1] = fmaxf(smaxp[2], smaxp[3]);
    }
}

// ---- iters 1..5: evaluate cem_i (scale=1). 4 lanes/candidate, 5 loads/lane.
__global__ void __launch_bounds__(256, 4) k_value(
        const float4* __restrict__ nz4, const float* __restrict__ target,
        const float* __restrict__ meanarr_i,
        float* __restrict__ v_out, float* __restrict__ wmax_out) {
    __shared__ float tgt[HAD], mnL[HAD];
    __shared__ float smax[4];
    const int tid = threadIdx.x, wg = blockIdx.x;
    const int lane = tid & 63, wid = tid >> 6;
    const int q = lane >> 4, s = lane & 15;
    const int n = wg * 64 + wid * 16 + s;
    const int h0 = QH0(q), cnt = QCN(q);

    float4 xs0 = nz4[(size_t)(h0 + 0) * NS + n];
    float4 xs1 = nz4[(size_t)(h0 + 1) * NS + n];
    float4 xs2 = nz4[(size_t)(h0 + 2) * NS + n];
    float4 xs3 = nz4[(size_t)(h0 + 3) * NS + n];
    const int h4 = (h0 + 4 > 17) ? 17 : h0 + 4;
    float4 xs4 = nz4[(size_t)h4 * NS + n];

    if (tid < HAD) { tgt[tid] = target[tid]; mnL[tid] = meanarr_i[tid]; }
    __syncthreads();

    const float w4 = (cnt == 5) ? 1.0f : 0.0f;
    float a2 = 0.f;
    {
        float c; int h;
        h = h0 + 0;
        c = clamp4f(mnL[h*4+0] + xs0.x) - tgt[h*4+0]; a2 += c*c;
        c = clamp4f(mnL[h*4+1] + xs0.y) - tgt[h*4+1]; a2 += c*c;
        c = clamp4f(mnL[h*4+2] + xs0.z) - tgt[h*4+2]; a2 += c*c;
        c = clamp4f(mnL[h*4+3] + xs0.w) - tgt[h*4+3]; a2 += c*c;
        h = h0 + 1;
        c = clamp4f(mnL[h*4+0] + xs1.x) - tgt[h*4+0]; a2 += c*c;
        c = clamp4f(mnL[h*4+1] + xs1.y) - tgt[h*4+1]; a2 += c*c;
        c = clamp4f(mnL[h*4+2] + xs1.z) - tgt[h*4+2]; a2 += c*c;
        c = clamp4f(mnL[h*4+3] + xs1.w) - tgt[h*4+3]; a2 += c*c;
        h = h0 + 2;
        c = clamp4f(mnL[h*4+0] + xs2.x) - tgt[h*4+0]; a2 += c*c;
        c = clamp4f(mnL[h*4+1] + xs2.y) - tgt[h*4+1]; a2 += c*c;
        c = clamp4f(mnL[h*4+2] + xs2.z) - tgt[h*4+2]; a2 += c*c;
        c = clamp4f(mnL[h*4+3] + xs2.w) - tgt[h*4+3]; a2 += c*c;
        h = h0 + 3;
        c = clamp4f(mnL[h*4+0] + xs3.x) - tgt[h*4+0]; a2 += c*c;
        c = clamp4f(mnL[h*4+1] + xs3.y) - tgt[h*4+1]; a2 += c*c;
        c = clamp4f(mnL[h*4+2] + xs3.z) - tgt[h*4+2]; a2 += c*c;
        c = clamp4f(mnL[h*4+3] + xs3.w) - tgt[h*4+3]; a2 += c*c;
        h = h4;
        c = clamp4f(mnL[h*4+0] + xs4.x) - tgt[h*4+0]; a2 += w4*c*c;
        c = clamp4f(mnL[h*4+1] + xs4.y) - tgt[h*4+1]; a2 += w4*c*c;
        c = clamp4f(mnL[h*4+2] + xs4.z) - tgt[h*4+2]; a2 += w4*c*c;
        c = clamp4f(mnL[h*4+3] + xs4.w) - tgt[h*4+3]; a2 += w4*c*c;
    }
    a2 += __shfl_xor(a2, 16);  a2 += __shfl_xor(a2, 32);
    const float vc = -a2;
    if (lane < 16) v_out[n] = vc;
    float m = vc;
#pragma unroll
    for (int off = 8; off; off >>= 1) m = fmaxf(m, __shfl_xor(m, off));
    if (lane == 0) smax[wid] = m;
    __syncthreads();
    if (tid == 0) {
        wmax_out[wg * 2 + 0] = fmaxf(smax[0], smax[1]);
        wmax_out[wg * 2 + 1] = fmaxf(smax[2], smax[3]);
    }
}

// ---- 1-block hierarchical reduce: gmax from chunk maxima -> survivors from
//      passing chunks -> exact top-64 via BOUNDED bitonic (replaces O(fc^2)
//      rank-select; fc<=64 fast path skips sort) -> softmax -> float4 gather
//      -> meanarr[iter+1].  is_last: exact argmax -> out.
__global__ void __launch_bounds__(1024) k_reduce(
        const float* __restrict__ pi, const float* __restrict__ noise_i,
        float* __restrict__ meanarr,
        const float* __restrict__ wmax_pi, const float* __restrict__ v_pi,
        const float* __restrict__ wmax_c, const float* __restrict__ v_c,
        float* __restrict__ out, int iter, int is_last) {
    __shared__ unsigned long long skey[SCAP];
    __shared__ unsigned long long top[64];
    __shared__ unsigned long long redk[16];
    __shared__ float buf[64 * 76];
    __shared__ float w64[64];
    __shared__ float mprev[HAD];
    __shared__ float redf[16];
    __shared__ unsigned s_fcnt;
    __shared__ float s_S, s_gmax;
    const int tid = threadIdx.x, lane = tid & 63, wid = tid >> 6;

    if (tid < HAD) mprev[tid] = meanarr[iter * HAD + tid];
    if (tid == 0) s_fcnt = 0u;
    __syncthreads();

    {
        float g = fmaxf(fmaxf(wmax_pi[tid], wmax_pi[tid + 1024]),
                        fmaxf(wmax_c[tid], wmax_c[tid + 1024]));
        for (int off = 32; off; off >>= 1) g = fmaxf(g, __shfl_xor(g, off));
        if (lane == 0) redf[wid] = g;
        __syncthreads();
        if (tid == 0) {
            float x = redf[0];
            for (int q = 1; q < 16; ++q) x = fmaxf(x, redf[q]);
            s_gmax = x;
        }
        __syncthreads();
    }
    const float gmax = s_gmax, thr = gmax - DELTA;

#pragma unroll
    for (int r = 0; r < 2; ++r) {
        const int c = tid + r * 1024;
        if (wmax_pi[c] >= thr) {
            const float4* v4 = (const float4*)v_pi + c * 8;
            for (int q = 0; q < 8; ++q) {
                float4 x = v4[q];
                float vv[4] = {x.x, x.y, x.z, x.w};
#pragma unroll
                for (int c2 = 0; c2 < 4; ++c2)
                    if (vv[c2] >= thr) {
                        unsigned p = atomicAdd(&s_fcnt, 1u);
                        if (p < SCAP) skey[p] = packkey(vv[c2], (unsigned)(c * 32 + q * 4 + c2));
                    }
            }
        }
        if (wmax_c[c] >= thr) {
            const float4* v4 = (const float4*)v_c + c * 8;
            for (int q = 0; q < 8; ++q) {
                float4 x = v4[q];
                float vv[4] = {x.x, x.y, x.z, x.w};
#pragma unroll
                for (int c2 = 0; c2 < 4; ++c2)
                    if (vv[c2] >= thr) {
                        unsigned p = atomicAdd(&s_fcnt, 1u);
                        if (p < SCAP) skey[p] = packkey(vv[c2], (unsigned)(NS + c * 32 + q * 4 + c2));
                    }
            }
        }
    }
    __syncthreads();
    unsigned fc = s_fcnt; if (fc > SCAP) fc = SCAP;
    const float pscale = (iter == 0) ? 0.5f : 1.0f;

    if (is_last) {
        unsigned long long bk = 0ull;
        for (unsigned k = tid; k < fc; k += 1024) if (skey[k] > bk) bk = skey[k];
        for (int off = 32; off; off >>= 1) {
            unsigned long long ok = __shfl_xor(bk, off);
            if (ok > bk) bk = ok;
        }
        if (lane == 0) redk[wid] = bk;
        __syncthreads();
        if (tid == 0) {
            unsigned long long b = redk[0];
            for (int q = 1; q < 16; ++q) if (redk[q] > b) b = redk[q];
            redk[0] = b;
        }
        __syncthreads();
        const unsigned idx = (unsigned)~(unsigned)(redk[0] & 0xFFFFFFFFull);
        if (tid < HAD) {
            const int h = tid >> 2, aa = tid & 3;
            float o;
            if (idx < NS) o = pi[(size_t)h * NS * AD + (size_t)idx * AD + aa];
            else o = clamp4f(mprev[tid] + pscale * noise_i[(size_t)h * NS * AD + (size_t)(idx - NS) * AD + aa]);
            out[tid] = o;
        }
        return;
    }

    int E;
    if (fc <= 64u) {
        // fast path: no selection needed (order irrelevant for the mean)
        if (tid < 64) top[tid] = (tid < (int)fc) ? skey[tid] : 0ull;
        __syncthreads();
        E = (int)fc;
    } else {
        // bounded bitonic sort desc on packed keys; top-64 = first 64
        unsigned P2 = 128; while (P2 < fc) P2 <<= 1;
        for (unsigned k = fc + tid; k < P2; k += 1024) skey[k] = 0ull;
        __syncthreads();
        for (unsigned kk = 2; kk <= P2; kk <<= 1) {
            for (unsigned j = kk >> 1; j; j >>= 1) {
                for (unsigned x = tid; x < P2; x += 1024) {
                    unsigned l = x ^ j;
                    if (l > x) {
                        unsigned long long k0 = skey[x], k1 = skey[l];
                        bool desc = ((x & kk) == 0);
                        if (desc ? (k0 < k1) : (k0 > k1)) { skey[x] = k1; skey[l] = k0; }
                    }
                }
                __syncthreads();
            }
        }
        if (tid < 64) top[tid] = skey[tid];
        __syncthreads();
        E = 64;
    }

    if (tid < 64) {
        float we = (tid < E) ? expf(decf((unsigned)(top[tid] >> 32)) - gmax) : 0.0f;
        w64[tid] = we;
        float s = we;
        for (int off = 32; off; off >>= 1) s += __shfl_xor(s, off);
        if (tid == 0) s_S = s;
    }
    __syncthreads();
    const float invS = 1.0f / (s_S * (1.0f + 1e-9f));

    const float4* pi4 = (const float4*)pi;
    const float4* nz4 = (const float4*)noise_i;
    for (int el = tid; el < 64 * H; el += 1024) {
        const int e = el / H, h = el - e * H;
        float ax = 0.f, ay = 0.f, az = 0.f, aw = 0.f;
        if (e < E) {
            const unsigned idx = (unsigned)~(unsigned)(top[e] & 0xFFFFFFFFull);
            float4 a;
            if (idx < NS) {
                a = pi4[(size_t)h * NS + idx];
            } else {
                float4 nz = nz4[(size_t)h * NS + (idx - NS)];
                a.x = clamp4f(mprev[h*4+0] + pscale * nz.x);
                a.y = clamp4f(mprev[h*4+1] + pscale * nz.y);
                a.z = clamp4f(mprev[h*4+2] + pscale * nz.z);
                a.w = clamp4f(mprev[h*4+3] + pscale * nz.w);
            }
            const float we = w64[e];
            ax = we * a.x; ay = we * a.y; az = we * a.z; aw = we * a.w;
        }
        buf[e * 76 + h * 4 + 0] = ax;
        buf[e * 76 + h * 4 + 1] = ay;
        buf[e * 76 + h * 4 + 2] = az;
        buf[e * 76 + h * 4 + 3] = aw;
    }
    __syncthreads();
    if (tid < HAD) {
        float s = 0.f;
#pragma unroll 8
        for (int e = 0; e < 64; ++e) s += buf[e * 76 + tid];
        meanarr[(iter + 1) * HAD + tid] = 0.1f * mprev[tid] + 0.9f * (s * invS);
    }
}

extern "C" void kernel_launch(void* const* d_in, const int* in_sizes, int n_in,
                              void* d_out, int out_size, void* d_ws, size_t ws_size,
                              hipStream_t stream) {
    const float* pi     = (const float*)d_in[0];
    const float* noise  = (const float*)d_in[1];
    const float* target = (const float*)d_in[2];
    float* out = (float*)d_out;

    float* ws = (float*)d_ws;
    float* meanarr = ws;                                   // 8*72 (pad 1024)
    float* wmax_pi = ws + 1024;                            // NCH
    float* wmax_c  = wmax_pi + NCH;                        // 6*NCH
    float* v_pi    = wmax_c + 6 * NCH;                     // NS
    float* v_c     = v_pi + NS;                            // 6*NS

    k_value0<<<1024, 256, 0, stream>>>((const float4*)pi, (const float4*)noise,
                                       target, meanarr, v_pi, wmax_pi, v_c, wmax_c);
    for (int i = 0; i < ITERS - 1; ++i) {
        const float* nzi = noise + (size_t)i * H * NS * AD;
        k_reduce<<<1, 1024, 0, stream>>>(pi, nzi, meanarr, wmax_pi, v_pi,
                                         wmax_c + (size_t)i * NCH,
                                         v_c + (size_t)i * NS, out, i, 0);
        const float* nzn = noise + (size_t)(i + 1) * H * NS * AD;
        k_value<<<1024, 256, 0, stream>>>((const float4*)nzn, target,
                                          meanarr + (size_t)(i + 1) * HAD,
                                          v_c + (size_t)(i + 1) * NS,
                                          wmax_c + (size_t)(i + 1) * NCH);
    }
    k_reduce<<<1, 1024, 0, stream>>>(pi, noise + (size_t)5 * H * NS * AD, meanarr,
                                     wmax_pi, v_pi,
                                     wmax_c + (size_t)5 * NCH,
                                     v_c + (size_t)5 * NS, out, 5, 1);
}

// Round 19
// 129.560 us; speedup vs baseline: 1.9152x; 1.2175x over previous
//
#include <hip/hip_runtime.h>
#include <math.h>

#define H 18
#define NS 65536
#define AD 4
#define HAD 72
#define ITERS 6
#define DELTA 16.0f
#define SCAP 4096
#define NCH 2048          // 32-candidate chunks per candidate set
#define NBIN 128
#define BINW 0.125f       // DELTA / NBIN

__device__ __forceinline__ unsigned encf(float f) {
    unsigned u = __float_as_uint(f);
    return (u & 0x80000000u) ? ~u : (u | 0x80000000u);
}
__device__ __forceinline__ float decf(unsigned u) {
    return __uint_as_float((u & 0x80000000u) ? (u & 0x7FFFFFFFu) : ~u);
}
__device__ __forceinline__ float clamp4f(float x) { return fminf(fmaxf(x, -4.0f), 4.0f); }
// descending u64 order == value desc, then index asc (matches top_k tie-break)
__device__ __forceinline__ unsigned long long packkey(float v, unsigned idx) {
    return ((unsigned long long)encf(v) << 32) | (unsigned long long)(~idx);
}

#define QH0(q) ((q) == 0 ? 0 : (q) == 1 ? 5 : (q) == 2 ? 10 : 14)
#define QCN(q) ((q) < 2 ? 5 : 4)

// ---- iter 0: evaluate pi and cem0. 4 lanes per candidate (h-quarters),
//      10 hoisted float4 loads per lane; 1024 blocks.
__global__ void __launch_bounds__(256, 4) k_value0(
        const float4* __restrict__ pi4, const float4* __restrict__ nz4,
        const float* __restrict__ target, float* __restrict__ meanarr,
        float* __restrict__ v_pi, float* __restrict__ wmax_pi,
        float* __restrict__ v_c0, float* __restrict__ wmax_c0) {
    __shared__ float tgt[HAD], mnL[HAD];
    __shared__ float smaxc[4], smaxp[4];
    const int tid = threadIdx.x, wg = blockIdx.x;
    const int lane = tid & 63, wid = tid >> 6;
    const int q = lane >> 4, s = lane & 15;
    const int n = wg * 64 + wid * 16 + s;
    const int h0 = QH0(q), cnt = QCN(q);

    float4 xs0 = nz4[(size_t)(h0 + 0) * NS + n];
    float4 xs1 = nz4[(size_t)(h0 + 1) * NS + n];
    float4 xs2 = nz4[(size_t)(h0 + 2) * NS + n];
    float4 xs3 = nz4[(size_t)(h0 + 3) * NS + n];
    const int h4 = (h0 + 4 > 17) ? 17 : h0 + 4;
    float4 xs4 = nz4[(size_t)h4 * NS + n];
    float4 ps0 = pi4[(size_t)(h0 + 0) * NS + n];
    float4 ps1 = pi4[(size_t)(h0 + 1) * NS + n];
    float4 ps2 = pi4[(size_t)(h0 + 2) * NS + n];
    float4 ps3 = pi4[(size_t)(h0 + 3) * NS + n];
    float4 ps4 = pi4[(size_t)h4 * NS + n];

    if (tid < HAD) {
        tgt[tid] = target[tid];
        float m0 = ((const float*)pi4)[(size_t)(tid >> 2) * NS * AD + (tid & 3)];
        mnL[tid] = m0;
        meanarr[tid] = m0;   // identical from all blocks: benign
    }
    __syncthreads();

    const float w4 = (cnt == 5) ? 1.0f : 0.0f;
    float a2 = 0.f, p2 = 0.f;
    {
        float c; int h;
        h = h0 + 0;
        c = clamp4f(mnL[h*4+0] + 0.5f*xs0.x) - tgt[h*4+0]; a2 += c*c;
        c = clamp4f(mnL[h*4+1] + 0.5f*xs0.y) - tgt[h*4+1]; a2 += c*c;
        c = clamp4f(mnL[h*4+2] + 0.5f*xs0.z) - tgt[h*4+2]; a2 += c*c;
        c = clamp4f(mnL[h*4+3] + 0.5f*xs0.w) - tgt[h*4+3]; a2 += c*c;
        c = ps0.x - tgt[h*4+0]; p2 += c*c;  c = ps0.y - tgt[h*4+1]; p2 += c*c;
        c = ps0.z - tgt[h*4+2]; p2 += c*c;  c = ps0.w - tgt[h*4+3]; p2 += c*c;
        h = h0 + 1;
        c = clamp4f(mnL[h*4+0] + 0.5f*xs1.x) - tgt[h*4+0]; a2 += c*c;
        c = clamp4f(mnL[h*4+1] + 0.5f*xs1.y) - tgt[h*4+1]; a2 += c*c;
        c = clamp4f(mnL[h*4+2] + 0.5f*xs1.z) - tgt[h*4+2]; a2 += c*c;
        c = clamp4f(mnL[h*4+3] + 0.5f*xs1.w) - tgt[h*4+3]; a2 += c*c;
        c = ps1.x - tgt[h*4+0]; p2 += c*c;  c = ps1.y - tgt[h*4+1]; p2 += c*c;
        c = ps1.z - tgt[h*4+2]; p2 += c*c;  c = ps1.w - tgt[h*4+3]; p2 += c*c;
        h = h0 + 2;
        c = clamp4f(mnL[h*4+0] + 0.5f*xs2.x) - tgt[h*4+0]; a2 += c*c;
        c = clamp4f(mnL[h*4+1] + 0.5f*xs2.y) - tgt[h*4+1]; a2 += c*c;
        c = clamp4f(mnL[h*4+2] + 0.5f*xs2.z) - tgt[h*4+2]; a2 += c*c;
        c = clamp4f(mnL[h*4+3] + 0.5f*xs2.w) - tgt[h*4+3]; a2 += c*c;
        c = ps2.x - tgt[h*4+0]; p2 += c*c;  c = ps2.y - tgt[h*4+1]; p2 += c*c;
        c = ps2.z - tgt[h*4+2]; p2 += c*c;  c = ps2.w - tgt[h*4+3]; p2 += c*c;
        h = h0 + 3;
        c = clamp4f(mnL[h*4+0] + 0.5f*xs3.x) - tgt[h*4+0]; a2 += c*c;
        c = clamp4f(mnL[h*4+1] + 0.5f*xs3.y) - tgt[h*4+1]; a2 += c*c;
        c = clamp4f(mnL[h*4+2] + 0.5f*xs3.z) - tgt[h*4+2]; a2 += c*c;
        c = clamp4f(mnL[h*4+3] + 0.5f*xs3.w) - tgt[h*4+3]; a2 += c*c;
        c = ps3.x - tgt[h*4+0]; p2 += c*c;  c = ps3.y - tgt[h*4+1]; p2 += c*c;
        c = ps3.z - tgt[h*4+2]; p2 += c*c;  c = ps3.w - tgt[h*4+3]; p2 += c*c;
        h = h4;
        c = clamp4f(mnL[h*4+0] + 0.5f*xs4.x) - tgt[h*4+0]; a2 += w4*c*c;
        c = clamp4f(mnL[h*4+1] + 0.5f*xs4.y) - tgt[h*4+1]; a2 += w4*c*c;
        c = clamp4f(mnL[h*4+2] + 0.5f*xs4.z) - tgt[h*4+2]; a2 += w4*c*c;
        c = clamp4f(mnL[h*4+3] + 0.5f*xs4.w) - tgt[h*4+3]; a2 += w4*c*c;
        c = ps4.x - tgt[h*4+0]; p2 += w4*c*c;  c = ps4.y - tgt[h*4+1]; p2 += w4*c*c;
        c = ps4.z - tgt[h*4+2]; p2 += w4*c*c;  c = ps4.w - tgt[h*4+3]; p2 += w4*c*c;
    }
    a2 += __shfl_xor(a2, 16);  a2 += __shfl_xor(a2, 32);
    p2 += __shfl_xor(p2, 16);  p2 += __shfl_xor(p2, 32);
    const float vc = -a2, vp = -p2;
    if (lane < 16) { v_c0[n] = vc; v_pi[n] = vp; }
    float mc = vc, mp = vp;
#pragma unroll
    for (int off = 8; off; off >>= 1) {
        mc = fmaxf(mc, __shfl_xor(mc, off));
        mp = fmaxf(mp, __shfl_xor(mp, off));
    }
    if (lane == 0) { smaxc[wid] = mc; smaxp[wid] = mp; }
    __syncthreads();
    if (tid == 0) {
        wmax_c0[wg * 2 + 0] = fmaxf(smaxc[0], smaxc[1]);
        wmax_c0[wg * 2 + 1] = fmaxf(smaxc[2], smaxc[3]);
        wmax_pi[wg * 2 + 0] = fmaxf(smaxp[0], smaxp[1]);
        wmax_pi[wg * 2 + 1] = fmaxf(smaxp[2], smaxp[3]);
    }
}

// ---- iters 1..5: evaluate cem_i (scale=1). 4 lanes/candidate, 5 loads/lane.
__global__ void __launch_bounds__(256, 4) k_value(
        const float4* __restrict__ nz4, const float* __restrict__ target,
        const float* __restrict__ meanarr_i,
        float* __restrict__ v_out, float* __restrict__ wmax_out) {
    __shared__ float tgt[HAD], mnL[HAD];
    __shared__ float smax[4];
    const int tid = threadIdx.x, wg = blockIdx.x;
    const int lane = tid & 63, wid = tid >> 6;
    const int q = lane >> 4, s = lane & 15;
    const int n = wg * 64 + wid * 16 + s;
    const int h0 = QH0(q), cnt = QCN(q);

    float4 xs0 = nz4[(size_t)(h0 + 0) * NS + n];
    float4 xs1 = nz4[(size_t)(h0 + 1) * NS + n];
    float4 xs2 = nz4[(size_t)(h0 + 2) * NS + n];
    float4 xs3 = nz4[(size_t)(h0 + 3) * NS + n];
    const int h4 = (h0 + 4 > 17) ? 17 : h0 + 4;
    float4 xs4 = nz4[(size_t)h4 * NS + n];

    if (tid < HAD) { tgt[tid] = target[tid]; mnL[tid] = meanarr_i[tid]; }
    __syncthreads();

    const float w4 = (cnt == 5) ? 1.0f : 0.0f;
    float a2 = 0.f;
    {
        float c; int h;
        h = h0 + 0;
        c = clamp4f(mnL[h*4+0] + xs0.x) - tgt[h*4+0]; a2 += c*c;
        c = clamp4f(mnL[h*4+1] + xs0.y) - tgt[h*4+1]; a2 += c*c;
        c = clamp4f(mnL[h*4+2] + xs0.z) - tgt[h*4+2]; a2 += c*c;
        c = clamp4f(mnL[h*4+3] + xs0.w) - tgt[h*4+3]; a2 += c*c;
        h = h0 + 1;
        c = clamp4f(mnL[h*4+0] + xs1.x) - tgt[h*4+0]; a2 += c*c;
        c = clamp4f(mnL[h*4+1] + xs1.y) - tgt[h*4+1]; a2 += c*c;
        c = clamp4f(mnL[h*4+2] + xs1.z) - tgt[h*4+2]; a2 += c*c;
        c = clamp4f(mnL[h*4+3] + xs1.w) - tgt[h*4+3]; a2 += c*c;
        h = h0 + 2;
        c = clamp4f(mnL[h*4+0] + xs2.x) - tgt[h*4+0]; a2 += c*c;
        c = clamp4f(mnL[h*4+1] + xs2.y) - tgt[h*4+1]; a2 += c*c;
        c = clamp4f(mnL[h*4+2] + xs2.z) - tgt[h*4+2]; a2 += c*c;
        c = clamp4f(mnL[h*4+3] + xs2.w) - tgt[h*4+3]; a2 += c*c;
        h = h0 + 3;
        c = clamp4f(mnL[h*4+0] + xs3.x) - tgt[h*4+0]; a2 += c*c;
        c = clamp4f(mnL[h*4+1] + xs3.y) - tgt[h*4+1]; a2 += c*c;
        c = clamp4f(mnL[h*4+2] + xs3.z) - tgt[h*4+2]; a2 += c*c;
        c = clamp4f(mnL[h*4+3] + xs3.w) - tgt[h*4+3]; a2 += c*c;
        h = h4;
        c = clamp4f(mnL[h*4+0] + xs4.x) - tgt[h*4+0]; a2 += w4*c*c;
        c = clamp4f(mnL[h*4+1] + xs4.y) - tgt[h*4+1]; a2 += w4*c*c;
        c = clamp4f(mnL[h*4+2] + xs4.z) - tgt[h*4+2]; a2 += w4*c*c;
        c = clamp4f(mnL[h*4+3] + xs4.w) - tgt[h*4+3]; a2 += w4*c*c;
    }
    a2 += __shfl_xor(a2, 16);  a2 += __shfl_xor(a2, 32);
    const float vc = -a2;
    if (lane < 16) v_out[n] = vc;
    float m = vc;
#pragma unroll
    for (int off = 8; off; off >>= 1) m = fmaxf(m, __shfl_xor(m, off));
    if (lane == 0) smax[wid] = m;
    __syncthreads();
    if (tid == 0) {
        wmax_out[wg * 2 + 0] = fmaxf(smax[0], smax[1]);
        wmax_out[wg * 2 + 1] = fmaxf(smax[2], smax[3]);
    }
}

// ---- 1-block reduce with ADAPTIVE threshold:
//      gmax -> 128-bin histogram of chunk maxima -> t = highest threshold
//      with >=64 qualifying chunks (so true top-64 all have v > t) ->
//      collect only chunks/values >= t (fc ~ 70-300) -> tiny rank-select
//      exact sorted top-64 -> softmax -> float4 gather -> meanarr[iter+1].
//      is_last: exact argmax -> out.
__global__ void __launch_bounds__(1024) k_reduce(
        const float* __restrict__ pi, const float* __restrict__ noise_i,
        float* __restrict__ meanarr,
        const float* __restrict__ wmax_pi, const float* __restrict__ v_pi,
        const float* __restrict__ wmax_c, const float* __restrict__ v_c,
        float* __restrict__ out, int iter, int is_last) {
    __shared__ unsigned long long skey[SCAP];
    __shared__ unsigned long long top[64];
    __shared__ unsigned long long redk[16];
    __shared__ float buf[64 * 76];
    __shared__ float w64[64];
    __shared__ float mprev[HAD];
    __shared__ float redf[16];
    __shared__ unsigned hist[NBIN];
    __shared__ unsigned s_fcnt;
    __shared__ float s_S, s_gmax, s_thr;
    const int tid = threadIdx.x, lane = tid & 63, wid = tid >> 6;

    if (tid < HAD) mprev[tid] = meanarr[iter * HAD + tid];
    if (tid == 0) s_fcnt = 0u;
    if (tid < NBIN) hist[tid] = 0u;
    __syncthreads();

    // ---- gmax over 4096 chunk maxima
    const float m0 = wmax_pi[tid], m1 = wmax_pi[tid + 1024];
    const float m2 = wmax_c[tid],  m3 = wmax_c[tid + 1024];
    {
        float g = fmaxf(fmaxf(m0, m1), fmaxf(m2, m3));
        for (int off = 32; off; off >>= 1) g = fmaxf(g, __shfl_xor(g, off));
        if (lane == 0) redf[wid] = g;
        __syncthreads();
        if (tid == 0) {
            float x = redf[0];
            for (int q = 1; q < 16; ++q) x = fmaxf(x, redf[q]);
            s_gmax = x;
        }
        __syncthreads();
    }
    const float gmax = s_gmax;

    // ---- histogram of chunk maxima over [gmax-16, gmax]
    {
        float mm[4] = {m0, m1, m2, m3};
#pragma unroll
        for (int r = 0; r < 4; ++r) {
            if (mm[r] >= gmax - DELTA) {
                int b = (int)((gmax - mm[r]) * (1.0f / BINW));
                if (b > NBIN - 1) b = NBIN - 1;
                atomicAdd(&hist[b], 1u);
            }
        }
    }
    __syncthreads();
    if (tid == 0) {
        unsigned cum = 0; int bstar = NBIN - 1;
        for (int b = 0; b < NBIN; ++b) {
            cum += hist[b];
            if (cum >= 64u) { bstar = b; break; }
        }
        s_thr = gmax - (float)(bstar + 1) * BINW;
    }
    __syncthreads();
    const float thr = s_thr;

    // ---- collect values >= thr from chunks with max >= thr
    {
        const float mm[4] = {m0, m1, m2, m3};
#pragma unroll
        for (int r = 0; r < 4; ++r) {
            if (mm[r] >= thr) {
                const int c = (r & 1) ? (tid + 1024) : tid;
                const float4* v4 = ((r < 2) ? (const float4*)v_pi : (const float4*)v_c) + c * 8;
                const unsigned base = ((r < 2) ? 0u : (unsigned)NS) + (unsigned)(c * 32);
                for (int qq = 0; qq < 8; ++qq) {
                    float4 x = v4[qq];
                    float vv[4] = {x.x, x.y, x.z, x.w};
#pragma unroll
                    for (int c2 = 0; c2 < 4; ++c2)
                        if (vv[c2] >= thr) {
                            unsigned p = atomicAdd(&s_fcnt, 1u);
                            if (p < SCAP) skey[p] = packkey(vv[c2], base + qq * 4 + c2);
                        }
                }
            }
        }
    }
    __syncthreads();
    unsigned fc = s_fcnt; if (fc > SCAP) fc = SCAP;
    const float pscale = (iter == 0) ? 0.5f : 1.0f;

    if (is_last) {
        unsigned long long bk = 0ull;
        for (unsigned k = tid; k < fc; k += 1024) if (skey[k] > bk) bk = skey[k];
        for (int off = 32; off; off >>= 1) {
            unsigned long long ok = __shfl_xor(bk, off);
            if (ok > bk) bk = ok;
        }
        if (lane == 0) redk[wid] = bk;
        __syncthreads();
        if (tid == 0) {
            unsigned long long b = redk[0];
            for (int q = 1; q < 16; ++q) if (redk[q] > b) b = redk[q];
            redk[0] = b;
        }
        __syncthreads();
        const unsigned idx = (unsigned)~(unsigned)(redk[0] & 0xFFFFFFFFull);
        if (tid < HAD) {
            const int h = tid >> 2, aa = tid & 3;
            float o;
            if (idx < NS) o = pi[(size_t)h * NS * AD + (size_t)idx * AD + aa];
            else o = clamp4f(mprev[tid] + pscale * noise_i[(size_t)h * NS * AD + (size_t)(idx - NS) * AD + aa]);
            out[tid] = o;
        }
        return;
    }

    // ---- exact sorted top-64 via rank-select (fc is small by construction)
    int E;
    if (fc <= 64u) {
        if (tid < 64) top[tid] = (tid < (int)fc) ? skey[tid] : 0ull;
        __syncthreads();
        E = (int)fc;
    } else {
        for (unsigned i = tid; i < fc; i += 1024) {
            unsigned long long k = skey[i];
            unsigned r = 0;
            for (unsigned j = 0; j < fc; ++j) r += (skey[j] > k) ? 1u : 0u;
            if (r < 64u) top[r] = k;
        }
        __syncthreads();
        E = 64;
    }

    if (tid < 64) {
        float we = (tid < E) ? expf(decf((unsigned)(top[tid] >> 32)) - gmax) : 0.0f;
        w64[tid] = we;
        float s = we;
        for (int off = 32; off; off >>= 1) s += __shfl_xor(s, off);
        if (tid == 0) s_S = s;
    }
    __syncthreads();
    const float invS = 1.0f / (s_S * (1.0f + 1e-9f));

    const float4* pi4 = (const float4*)pi;
    const float4* nz4 = (const float4*)noise_i;
    for (int el = tid; el < 64 * H; el += 1024) {
        const int e = el / H, h = el - e * H;
        float ax = 0.f, ay = 0.f, az = 0.f, aw = 0.f;
        if (e < E) {
            const unsigned idx = (unsigned)~(unsigned)(top[e] & 0xFFFFFFFFull);
            float4 a;
            if (idx < NS) {
                a = pi4[(size_t)h * NS + idx];
            } else {
                float4 nz = nz4[(size_t)h * NS + (idx - NS)];
                a.x = clamp4f(mprev[h*4+0] + pscale * nz.x);
                a.y = clamp4f(mprev[h*4+1] + pscale * nz.y);
                a.z = clamp4f(mprev[h*4+2] + pscale * nz.z);
                a.w = clamp4f(mprev[h*4+3] + pscale * nz.w);
            }
            const float we = w64[e];
            ax = we * a.x; ay = we * a.y; az = we * a.z; aw = we * a.w;
        }
        buf[e * 76 + h * 4 + 0] = ax;
        buf[e * 76 + h * 4 + 1] = ay;
        buf[e * 76 + h * 4 + 2] = az;
        buf[e * 76 + h * 4 + 3] = aw;
    }
    __syncthreads();
    if (tid < HAD) {
        float s = 0.f;
#pragma unroll 8
        for (int e = 0; e < 64; ++e) s += buf[e * 76 + tid];
        meanarr[(iter + 1) * HAD + tid] = 0.1f * mprev[tid] + 0.9f * (s * invS);
    }
}

extern "C" void kernel_launch(void* const* d_in, const int* in_sizes, int n_in,
                              void* d_out, int out_size, void* d_ws, size_t ws_size,
                              hipStream_t stream) {
    const float* pi     = (const float*)d_in[0];
    const float* noise  = (const float*)d_in[1];
    const float* target = (const float*)d_in[2];
    float* out = (float*)d_out;

    float* ws = (float*)d_ws;
    float* meanarr = ws;                                   // 8*72 (pad 1024)
    float* wmax_pi = ws + 1024;                            // NCH
    float* wmax_c  = wmax_pi + NCH;                        // 6*NCH
    float* v_pi    = wmax_c + 6 * NCH;                     // NS
    float* v_c     = v_pi + NS;                            // 6*NS

    k_value0<<<1024, 256, 0, stream>>>((const float4*)pi, (const float4*)noise,
                                       target, meanarr, v_pi, wmax_pi, v_c, wmax_c);
    for (int i = 0; i < ITERS - 1; ++i) {
        const float* nzi = noise + (size_t)i * H * NS * AD;
        k_reduce<<<1, 1024, 0, stream>>>(pi, nzi, meanarr, wmax_pi, v_pi,
                                         wmax_c + (size_t)i * NCH,
                                         v_c + (size_t)i * NS, out, i, 0);
        const float* nzn = noise + (size_t)(i + 1) * H * NS * AD;
        k_value<<<1024, 256, 0, stream>>>((const float4*)nzn, target,
                                          meanarr + (size_t)(i + 1) * HAD,
                                          v_c + (size_t)(i + 1) * NS,
                                          wmax_c + (size_t)(i + 1) * NCH);
    }
    k_reduce<<<1, 1024, 0, stream>>>(pi, noise + (size_t)5 * H * NS * AD, meanarr,
                                     wmax_pi, v_pi,
                                     wmax_c + (size_t)5 * NCH,
                                     v_c + (size_t)5 * NS, out, 5, 1);
}